// Round 1
// baseline (1984.887 us; speedup 1.0000x reference)
//
#include <hip/hip_runtime.h>

#define NEG_SLOPE 0.2f
static const int N_NODES = 1395;
static const int N_EDGES = 44640;

// ---------------- GCN kernels ----------------

// xw1 = (x with cols 0..2 zeroed) @ W1 ; zero deg/acc1/acc2
__global__ void k_prep(const float* __restrict__ x, const float* __restrict__ W1,
                       float* __restrict__ xw1, float* __restrict__ deg,
                       float* __restrict__ acc1, float* __restrict__ acc2, int N) {
    int i = blockIdx.x * blockDim.x + threadIdx.x;
    if (i >= N) return;
    float x3 = x[i * 6 + 3], x4 = x[i * 6 + 4], x5 = x[i * 6 + 5];
#pragma unroll
    for (int j = 0; j < 3; ++j) {
        xw1[i * 3 + j] = x3 * W1[3 * 3 + j] + x4 * W1[4 * 3 + j] + x5 * W1[5 * 3 + j];
        acc1[i * 3 + j] = 0.f;
        acc2[i * 3 + j] = 0.f;
    }
    deg[i] = 0.f;
}

__global__ void k_deg(const int* __restrict__ ei, float* __restrict__ deg, int E) {
    int e = blockIdx.x * blockDim.x + threadIdx.x;
    if (e >= E) return;
    atomicAdd(&deg[ei[E + e]], 1.0f);
}

// dinv = 1/sqrt(deg + 1)  (self loop included; always > 0)
__global__ void k_dinv(float* __restrict__ deg, int N) {
    int i = blockIdx.x * blockDim.x + threadIdx.x;
    if (i >= N) return;
    deg[i] = 1.0f / sqrtf(deg[i] + 1.0f);
}

// acc[dst] += dinv[src]*dinv[dst] * xw[src]
__global__ void k_scatter(const int* __restrict__ ei, const float* __restrict__ dinv,
                          const float* __restrict__ xw, float* __restrict__ acc, int E) {
    int e = blockIdx.x * blockDim.x + threadIdx.x;
    if (e >= E) return;
    int s = ei[e], d = ei[E + e];
    float w = dinv[s] * dinv[d];
    atomicAdd(&acc[d * 3 + 0], w * xw[s * 3 + 0]);
    atomicAdd(&acc[d * 3 + 1], w * xw[s * 3 + 1]);
    atomicAdd(&acc[d * 3 + 2], w * xw[s * 3 + 2]);
}

// h = leaky(acc1 + dinv^2*xw1 + b1); xw2 = h @ W2
__global__ void k_node2(const float* __restrict__ acc1, const float* __restrict__ dinv,
                        const float* __restrict__ xw1, const float* __restrict__ b1,
                        const float* __restrict__ W2, float* __restrict__ xw2, int N) {
    int i = blockIdx.x * blockDim.x + threadIdx.x;
    if (i >= N) return;
    float di2 = dinv[i] * dinv[i];
    float h[3];
#pragma unroll
    for (int j = 0; j < 3; ++j) {
        float t = acc1[i * 3 + j] + di2 * xw1[i * 3 + j] + b1[j];
        h[j] = t >= 0.f ? t : NEG_SLOPE * t;
    }
#pragma unroll
    for (int j = 0; j < 3; ++j)
        xw2[i * 3 + j] = h[0] * W2[0 * 3 + j] + h[1] * W2[1 * 3 + j] + h[2] * W2[2 * 3 + j];
}

// v = leaky(acc2 + dinv^2*xw2 + b2)  (flattened [N*3] = 4185)
__global__ void k_node3(const float* __restrict__ acc2, const float* __restrict__ dinv,
                        const float* __restrict__ xw2, const float* __restrict__ b2,
                        float* __restrict__ v, int N) {
    int i = blockIdx.x * blockDim.x + threadIdx.x;
    if (i >= N) return;
    float di2 = dinv[i] * dinv[i];
#pragma unroll
    for (int j = 0; j < 3; ++j) {
        float t = acc2[i * 3 + j] + di2 * xw2[i * 3 + j] + b2[j];
        v[i * 3 + j] = t >= 0.f ? t : NEG_SLOPE * t;
    }
}

// ---------------- GEMV ----------------

__device__ __forceinline__ float block_reduce_sum(float s) {
#pragma unroll
    for (int o = 32; o > 0; o >>= 1) s += __shfl_down(s, o, 64);
    __shared__ float parts[8];
    int lane = threadIdx.x & 63, wid = threadIdx.x >> 6;
    int nw = blockDim.x >> 6;
    if (lane == 0) parts[wid] = s;
    __syncthreads();
    if (threadIdx.x == 0) {
        for (int w = 1; w < nw; ++w) s += parts[w];
    }
    return s;  // valid only on thread 0
}

// y[r] = dot(W[r,:], x) + b[r], scalar loads (any C)
__global__ void k_gemv(const float* __restrict__ W, const float* __restrict__ x,
                       const float* __restrict__ b, float* __restrict__ y, int C) {
    int r = blockIdx.x;
    const float* row = W + (size_t)r * (size_t)C;
    float s = 0.f;
    for (int c = threadIdx.x; c < C; c += blockDim.x) s += row[c] * x[c];
    s = block_reduce_sum(s);
    if (threadIdx.x == 0) y[r] = s + b[r];
}

// float4 version: requires C % 4 == 0 (rows then stay 16B-aligned)
__global__ void k_gemv4(const float* __restrict__ W, const float* __restrict__ x,
                        const float* __restrict__ b, float* __restrict__ y, int C) {
    int r = blockIdx.x;
    const float4* row = (const float4*)(W + (size_t)r * (size_t)C);
    const float4* xv = (const float4*)x;
    int C4 = C >> 2;
    float s = 0.f;
    for (int c = threadIdx.x; c < C4; c += blockDim.x) {
        float4 a = row[c];
        float4 v = xv[c];
        s += a.x * v.x + a.y * v.y + a.z * v.z + a.w * v.w;
    }
    s = block_reduce_sum(s);
    if (threadIdx.x == 0) y[r] = s + b[r];
}

// ---------------- direct conv (valid, stride 1) ----------------
// grid.x = Cout * tilesPerCo; per-co weights staged in LDS.
__global__ void k_conv(const float* __restrict__ in, const float* __restrict__ w,
                       const float* __restrict__ b, float* __restrict__ out,
                       int Cin, int H, int W, int K, int Hout, int Wout, int tilesPerCo) {
    int co = blockIdx.x / tilesPerCo;
    int tile = blockIdx.x % tilesPerCo;
    extern __shared__ float wl[];
    int wn = Cin * K * K;
    for (int t = threadIdx.x; t < wn; t += blockDim.x) wl[t] = w[co * wn + t];
    __syncthreads();
    int npix = Hout * Wout;
    float bias = b[co];
    for (int p = tile * blockDim.x + threadIdx.x; p < npix; p += tilesPerCo * blockDim.x) {
        int oh = p / Wout, ow = p - oh * Wout;
        float s = bias;
        const float* wp = wl;
        for (int ci = 0; ci < Cin; ++ci) {
            const float* ip = in + ((size_t)ci * H + oh) * W + ow;
            for (int kh = 0; kh < K; ++kh) {
#pragma unroll 4
                for (int kw = 0; kw < K; ++kw) s += ip[kh * W + kw] * wp[kh * K + kw];
            }
            wp += K * K;
        }
        out[((size_t)co * Hout + oh) * Wout + ow] = s;
    }
}

// ---------------- launcher ----------------

extern "C" void kernel_launch(void* const* d_in, const int* in_sizes, int n_in,
                              void* d_out, int out_size, void* d_ws, size_t ws_size,
                              hipStream_t stream) {
    const float* x      = (const float*)d_in[0];
    const int*   ei     = (const int*)d_in[1];
    const float* W1     = (const float*)d_in[2];
    const float* b1     = (const float*)d_in[3];
    const float* W2     = (const float*)d_in[4];
    const float* b2     = (const float*)d_in[5];
    const float* fc1_w  = (const float*)d_in[6];
    const float* fc1_b  = (const float*)d_in[7];
    const float* fc2_w  = (const float*)d_in[8];
    const float* fc2_b  = (const float*)d_in[9];
    const float* c1_w   = (const float*)d_in[10];
    const float* c1_b   = (const float*)d_in[11];
    const float* c2_w   = (const float*)d_in[12];
    const float* c2_b   = (const float*)d_in[13];
    const float* c3_w   = (const float*)d_in[14];
    const float* c3_b   = (const float*)d_in[15];
    const float* c4_w   = (const float*)d_in[16];
    const float* c4_b   = (const float*)d_in[17];
    const float* fc3_w  = (const float*)d_in[18];
    const float* fc3_b  = (const float*)d_in[19];
    const float* fc4_w  = (const float*)d_in[20];
    const float* fc4_b  = (const float*)d_in[21];
    const float* fc5_w  = (const float*)d_in[22];
    const float* fc5_b  = (const float*)d_in[23];
    float* out = (float*)d_out;

    float* ws = (float*)d_ws;
    size_t off = 0;
    auto alloc = [&](size_t n) { float* p = ws + off; off += (n + 3) & ~(size_t)3; return p; };
    const int N = N_NODES, E = N_EDGES;
    float* deg  = alloc(N);        // becomes dinv after k_dinv
    float* xw1  = alloc(N * 3);
    float* acc1 = alloc(N * 3);
    float* xw2  = alloc(N * 3);
    float* acc2 = alloc(N * 3);
    float* v    = alloc(4185);
    float* y1   = alloc(2048);
    float* y2   = alloc(4096);     // = 64x64 image
    float* i1   = alloc(32 * 58 * 58);
    float* i2   = alloc(32 * 54 * 54);
    float* i3   = alloc(64 * 52 * 52);
    float* i4   = alloc(64 * 50 * 50);
    float* y3   = alloc(2048);
    float* y4   = alloc(2048);
    (void)ws_size; (void)in_sizes; (void)n_in; (void)out_size;

    int nb = (N + 255) / 256;
    int eb = (E + 255) / 256;

    // GCN layer 1
    k_prep<<<nb, 256, 0, stream>>>(x, W1, xw1, deg, acc1, acc2, N);
    k_deg<<<eb, 256, 0, stream>>>(ei, deg, E);
    k_dinv<<<nb, 256, 0, stream>>>(deg, N);
    k_scatter<<<eb, 256, 0, stream>>>(ei, deg, xw1, acc1, E);
    k_node2<<<nb, 256, 0, stream>>>(acc1, deg, xw1, b1, W2, xw2, N);
    // GCN layer 2
    k_scatter<<<eb, 256, 0, stream>>>(ei, deg, xw2, acc2, E);
    k_node3<<<nb, 256, 0, stream>>>(acc2, deg, xw2, b2, v, N);

    // fc1: [2048,4185] (C odd -> scalar), fc2: [4096,2048]
    k_gemv<<<2048, 256, 0, stream>>>(fc1_w, v, fc1_b, y1, 4185);
    k_gemv4<<<4096, 256, 0, stream>>>(fc2_w, y1, fc2_b, y2, 2048);

    // convs
    k_conv<<<32 * 8,  256, 1 * 7 * 7 * 4,   stream>>>(y2, c1_w, c1_b, i1, 1, 64, 64, 7, 58, 58, 8);
    k_conv<<<32 * 12, 256, 32 * 5 * 5 * 4,  stream>>>(i1, c2_w, c2_b, i2, 32, 58, 58, 5, 54, 54, 12);
    k_conv<<<64 * 11, 256, 32 * 3 * 3 * 4,  stream>>>(i2, c3_w, c3_b, i3, 32, 54, 54, 3, 52, 52, 11);
    k_conv<<<64 * 10, 256, 64 * 3 * 3 * 4,  stream>>>(i3, c4_w, c4_b, i4, 64, 52, 52, 3, 50, 50, 10);

    // fc3 (the 1.31 GB monster), fc4, fc5
    k_gemv4<<<2048, 256, 0, stream>>>(fc3_w, i4, fc3_b, y3, 160000);
    k_gemv4<<<2048, 256, 0, stream>>>(fc4_w, y3, fc4_b, y4, 2048);
    k_gemv4<<<48, 256, 0, stream>>>(fc5_w, y4, fc5_b, out, 2048);
}

// Round 2
// 1881.941 us; speedup vs baseline: 1.0547x; 1.0547x over previous
//
#include <hip/hip_runtime.h>

#define NEG_SLOPE 0.2f
static const int N_NODES = 1395;
static const int N_EDGES = 44640;

// ---------------- GCN kernels ----------------

__global__ void k_prep(const float* __restrict__ x, const float* __restrict__ W1,
                       float* __restrict__ xw1, float* __restrict__ deg,
                       float* __restrict__ acc1, float* __restrict__ acc2, int N) {
    int i = blockIdx.x * blockDim.x + threadIdx.x;
    if (i >= N) return;
    float x3 = x[i * 6 + 3], x4 = x[i * 6 + 4], x5 = x[i * 6 + 5];
#pragma unroll
    for (int j = 0; j < 3; ++j) {
        xw1[i * 3 + j] = x3 * W1[3 * 3 + j] + x4 * W1[4 * 3 + j] + x5 * W1[5 * 3 + j];
        acc1[i * 3 + j] = 0.f;
        acc2[i * 3 + j] = 0.f;
    }
    deg[i] = 0.f;
}

__global__ void k_deg(const int* __restrict__ ei, float* __restrict__ deg, int E) {
    int e = blockIdx.x * blockDim.x + threadIdx.x;
    if (e >= E) return;
    atomicAdd(&deg[ei[E + e]], 1.0f);
}

__global__ void k_dinv(float* __restrict__ deg, int N) {
    int i = blockIdx.x * blockDim.x + threadIdx.x;
    if (i >= N) return;
    deg[i] = 1.0f / sqrtf(deg[i] + 1.0f);
}

__global__ void k_scatter(const int* __restrict__ ei, const float* __restrict__ dinv,
                          const float* __restrict__ xw, float* __restrict__ acc, int E) {
    int e = blockIdx.x * blockDim.x + threadIdx.x;
    if (e >= E) return;
    int s = ei[e], d = ei[E + e];
    float w = dinv[s] * dinv[d];
    atomicAdd(&acc[d * 3 + 0], w * xw[s * 3 + 0]);
    atomicAdd(&acc[d * 3 + 1], w * xw[s * 3 + 1]);
    atomicAdd(&acc[d * 3 + 2], w * xw[s * 3 + 2]);
}

__global__ void k_node2(const float* __restrict__ acc1, const float* __restrict__ dinv,
                        const float* __restrict__ xw1, const float* __restrict__ b1,
                        const float* __restrict__ W2, float* __restrict__ xw2, int N) {
    int i = blockIdx.x * blockDim.x + threadIdx.x;
    if (i >= N) return;
    float di2 = dinv[i] * dinv[i];
    float h[3];
#pragma unroll
    for (int j = 0; j < 3; ++j) {
        float t = acc1[i * 3 + j] + di2 * xw1[i * 3 + j] + b1[j];
        h[j] = t >= 0.f ? t : NEG_SLOPE * t;
    }
#pragma unroll
    for (int j = 0; j < 3; ++j)
        xw2[i * 3 + j] = h[0] * W2[0 * 3 + j] + h[1] * W2[1 * 3 + j] + h[2] * W2[2 * 3 + j];
}

__global__ void k_node3(const float* __restrict__ acc2, const float* __restrict__ dinv,
                        const float* __restrict__ xw2, const float* __restrict__ b2,
                        float* __restrict__ v, int N) {
    int i = blockIdx.x * blockDim.x + threadIdx.x;
    if (i >= N) return;
    float di2 = dinv[i] * dinv[i];
#pragma unroll
    for (int j = 0; j < 3; ++j) {
        float t = acc2[i * 3 + j] + di2 * xw2[i * 3 + j] + b2[j];
        v[i * 3 + j] = t >= 0.f ? t : NEG_SLOPE * t;
    }
}

// ---------------- GEMV ----------------

__device__ __forceinline__ float block_reduce_sum(float s) {
#pragma unroll
    for (int o = 32; o > 0; o >>= 1) s += __shfl_down(s, o, 64);
    __shared__ float parts[8];
    int lane = threadIdx.x & 63, wid = threadIdx.x >> 6;
    int nw = blockDim.x >> 6;
    if (lane == 0) parts[wid] = s;
    __syncthreads();
    if (threadIdx.x == 0) {
        for (int w = 1; w < nw; ++w) s += parts[w];
    }
    return s;  // valid only on thread 0
}

// scalar GEMV (any C), 4 accumulator chains for MLP
__global__ void k_gemv(const float* __restrict__ W, const float* __restrict__ x,
                       const float* __restrict__ b, float* __restrict__ y, int C) {
    int r = blockIdx.x;
    const float* row = W + (size_t)r * (size_t)C;
    int step = blockDim.x;
    float a0 = 0.f, a1 = 0.f, a2 = 0.f, a3 = 0.f;
    int c = threadIdx.x;
    for (; c + 3 * step < C; c += 4 * step) {
        a0 += row[c] * x[c];
        a1 += row[c + step] * x[c + step];
        a2 += row[c + 2 * step] * x[c + 2 * step];
        a3 += row[c + 3 * step] * x[c + 3 * step];
    }
    for (; c < C; c += step) a0 += row[c] * x[c];
    float s = block_reduce_sum(a0 + a1 + a2 + a3);
    if (threadIdx.x == 0) y[r] = s + b[r];
}

// small float4 GEMV, one block per row (fc5)
__global__ void k_gemv4(const float* __restrict__ W, const float* __restrict__ x,
                        const float* __restrict__ b, float* __restrict__ y, int C) {
    int r = blockIdx.x;
    const float4* row = (const float4*)(W + (size_t)r * (size_t)C);
    const float4* xv = (const float4*)x;
    int C4 = C >> 2;
    float s = 0.f;
    for (int c = threadIdx.x; c < C4; c += blockDim.x) {
        float4 a = row[c];
        float4 v = xv[c];
        s += a.x * v.x + a.y * v.y + a.z * v.z + a.w * v.w;
    }
    s = block_reduce_sum(s);
    if (threadIdx.x == 0) y[r] = s + b[r];
}

// column-split GEMV stage A: partial[r*S+s] = dot over chunk s of row r.
// C must be divisible by 4. 4 independent acc chains + 4x unroll.
__global__ void k_gemv_part(const float* __restrict__ W, const float* __restrict__ x,
                            float* __restrict__ partial, int C4, int S) {
    int r = blockIdx.x / S, s = blockIdx.x % S;
    int c0 = (int)(((long long)C4 * s) / S);
    int c1 = (int)(((long long)C4 * (s + 1)) / S);
    const float4* row = (const float4*)W + (size_t)r * (size_t)C4;
    const float4* xv = (const float4*)x;
    int step = blockDim.x;
    float a0 = 0.f, a1 = 0.f, a2 = 0.f, a3 = 0.f;
    int c = c0 + threadIdx.x;
    for (; c + 3 * step < c1; c += 4 * step) {
        float4 w0 = row[c];            float4 v0 = xv[c];
        float4 w1 = row[c + step];     float4 v1 = xv[c + step];
        float4 w2 = row[c + 2 * step]; float4 v2 = xv[c + 2 * step];
        float4 w3 = row[c + 3 * step]; float4 v3 = xv[c + 3 * step];
        a0 += w0.x * v0.x + w0.y * v0.y + w0.z * v0.z + w0.w * v0.w;
        a1 += w1.x * v1.x + w1.y * v1.y + w1.z * v1.z + w1.w * v1.w;
        a2 += w2.x * v2.x + w2.y * v2.y + w2.z * v2.z + w2.w * v2.w;
        a3 += w3.x * v3.x + w3.y * v3.y + w3.z * v3.z + w3.w * v3.w;
    }
    for (; c < c1; c += step) {
        float4 w0 = row[c]; float4 v0 = xv[c];
        a0 += w0.x * v0.x + w0.y * v0.y + w0.z * v0.z + w0.w * v0.w;
    }
    float ssum = block_reduce_sum(a0 + a1 + a2 + a3);
    if (threadIdx.x == 0) partial[r * S + s] = ssum;
}

// stage B: y[r] = b[r] + sum_s partial[r*S+s]
__global__ void k_gemv_fin(const float* __restrict__ partial, const float* __restrict__ b,
                           float* __restrict__ y, int R, int S) {
    int r = blockIdx.x * blockDim.x + threadIdx.x;
    if (r >= R) return;
    float ssum = b[r];
    for (int s = 0; s < S; ++s) ssum += partial[r * S + s];
    y[r] = ssum;
}

// ---------------- direct conv (valid, stride 1), K templated for full unroll ----
template <int K>
__global__ void k_conv(const float* __restrict__ in, const float* __restrict__ w,
                       const float* __restrict__ b, float* __restrict__ out,
                       int Cin, int H, int W, int Hout, int Wout, int tilesPerCo) {
    int co = blockIdx.x / tilesPerCo;
    int tile = blockIdx.x % tilesPerCo;
    extern __shared__ float wl[];
    int wn = Cin * K * K;
    for (int t = threadIdx.x; t < wn; t += blockDim.x) wl[t] = w[co * wn + t];
    __syncthreads();
    int npix = Hout * Wout;
    float bias = b[co];
    for (int p = tile * blockDim.x + threadIdx.x; p < npix; p += tilesPerCo * blockDim.x) {
        int oh = p / Wout, ow = p - oh * Wout;
        float s = bias;
        const float* wp = wl;
        for (int ci = 0; ci < Cin; ++ci) {
            const float* ip = in + ((size_t)ci * H + oh) * W + ow;
#pragma unroll
            for (int kh = 0; kh < K; ++kh) {
#pragma unroll
                for (int kw = 0; kw < K; ++kw) s += ip[kh * W + kw] * wp[kh * K + kw];
            }
            wp += K * K;
        }
        out[((size_t)co * Hout + oh) * Wout + ow] = s;
    }
}

// ---------------- launcher ----------------

extern "C" void kernel_launch(void* const* d_in, const int* in_sizes, int n_in,
                              void* d_out, int out_size, void* d_ws, size_t ws_size,
                              hipStream_t stream) {
    const float* x      = (const float*)d_in[0];
    const int*   ei     = (const int*)d_in[1];
    const float* W1     = (const float*)d_in[2];
    const float* b1     = (const float*)d_in[3];
    const float* W2     = (const float*)d_in[4];
    const float* b2     = (const float*)d_in[5];
    const float* fc1_w  = (const float*)d_in[6];
    const float* fc1_b  = (const float*)d_in[7];
    const float* fc2_w  = (const float*)d_in[8];
    const float* fc2_b  = (const float*)d_in[9];
    const float* c1_w   = (const float*)d_in[10];
    const float* c1_b   = (const float*)d_in[11];
    const float* c2_w   = (const float*)d_in[12];
    const float* c2_b   = (const float*)d_in[13];
    const float* c3_w   = (const float*)d_in[14];
    const float* c3_b   = (const float*)d_in[15];
    const float* c4_w   = (const float*)d_in[16];
    const float* c4_b   = (const float*)d_in[17];
    const float* fc3_w  = (const float*)d_in[18];
    const float* fc3_b  = (const float*)d_in[19];
    const float* fc4_w  = (const float*)d_in[20];
    const float* fc4_b  = (const float*)d_in[21];
    const float* fc5_w  = (const float*)d_in[22];
    const float* fc5_b  = (const float*)d_in[23];
    float* out = (float*)d_out;

    float* ws = (float*)d_ws;
    size_t off = 0;
    auto alloc = [&](size_t n) { float* p = ws + off; off += (n + 3) & ~(size_t)3; return p; };
    const int N = N_NODES, E = N_EDGES;
    float* deg  = alloc(N);
    float* xw1  = alloc(N * 3);
    float* acc1 = alloc(N * 3);
    float* xw2  = alloc(N * 3);
    float* acc2 = alloc(N * 3);
    float* v    = alloc(4185);
    float* y1   = alloc(2048);
    float* y2   = alloc(4096);
    float* i1   = alloc(32 * 58 * 58);
    float* i2   = alloc(32 * 54 * 54);
    float* i3   = alloc(64 * 52 * 52);
    float* i4   = alloc(64 * 50 * 50);
    float* y3   = alloc(2048);
    float* y4   = alloc(2048);
    float* pbuf = alloc(2048 * 8);   // partials: max(2048*8, 4096*2, 2048*2)
    (void)ws_size; (void)in_sizes; (void)n_in; (void)out_size;

    int nb = (N + 255) / 256;
    int eb = (E + 255) / 256;

    // GCN
    k_prep<<<nb, 256, 0, stream>>>(x, W1, xw1, deg, acc1, acc2, N);
    k_deg<<<eb, 256, 0, stream>>>(ei, deg, E);
    k_dinv<<<nb, 256, 0, stream>>>(deg, N);
    k_scatter<<<eb, 256, 0, stream>>>(ei, deg, xw1, acc1, E);
    k_node2<<<nb, 256, 0, stream>>>(acc1, deg, xw1, b1, W2, xw2, N);
    k_scatter<<<eb, 256, 0, stream>>>(ei, deg, xw2, acc2, E);
    k_node3<<<nb, 256, 0, stream>>>(acc2, deg, xw2, b2, v, N);

    // fc1 [2048,4185] scalar; fc2 [4096,2048] split S=2
    k_gemv<<<2048, 256, 0, stream>>>(fc1_w, v, fc1_b, y1, 4185);
    k_gemv_part<<<4096 * 2, 256, 0, stream>>>(fc2_w, y1, pbuf, 2048 / 4, 2);
    k_gemv_fin<<<(4096 + 255) / 256, 256, 0, stream>>>(pbuf, fc2_b, y2, 4096, 2);

    // convs (grid >= 512 blocks each, K fully unrolled)
    k_conv<7><<<32 * 16, 256, 1 * 7 * 7 * 4,  stream>>>(y2, c1_w, c1_b, i1, 1, 64, 64, 58, 58, 16);
    k_conv<5><<<32 * 16, 256, 32 * 5 * 5 * 4, stream>>>(i1, c2_w, c2_b, i2, 32, 58, 58, 54, 54, 16);
    k_conv<3><<<64 * 8,  256, 32 * 3 * 3 * 4, stream>>>(i2, c3_w, c3_b, i3, 32, 54, 54, 52, 52, 8);
    k_conv<3><<<64 * 8,  256, 64 * 3 * 3 * 4, stream>>>(i3, c4_w, c4_b, i4, 64, 52, 52, 50, 50, 8);

    // fc3 [2048,160000] split S=8 (16384 blocks); fc4 [2048,2048] split S=2; fc5 small
    k_gemv_part<<<2048 * 8, 256, 0, stream>>>(fc3_w, i4, pbuf, 160000 / 4, 8);
    k_gemv_fin<<<(2048 + 255) / 256, 256, 0, stream>>>(pbuf, fc3_b, y3, 2048, 8);
    k_gemv_part<<<2048 * 2, 256, 0, stream>>>(fc4_w, y3, pbuf, 2048 / 4, 2);
    k_gemv_fin<<<(2048 + 255) / 256, 256, 0, stream>>>(pbuf, fc4_b, y4, 2048, 2);
    k_gemv4<<<48, 256, 0, stream>>>(fc5_w, y4, fc5_b, out, 2048);
}